// Round 5
// baseline (585.388 us; speedup 1.0000x reference)
//
#include <hip/hip_runtime.h>

// BilinearResNet fused forward, round 9.
// Rounds 4-8 post-mortem: four structurally different staged-LDS schedules
// (DMA 2-buf / DMA 3-buf counted / 32-wave DMA / reg-staged T14) all cluster
// at 120-196us vs a ~33us memory roofline, across occupancy 24-73%. The
// shared invariants were the per-chunk whole-block barrier (burst-then-wait,
// gated by the tail of a GPU-wide 16.8MB burst) and the 256B-per-row chunk
// geometry. The harness's own fillBuffer kernel hits 6.8 TB/s (85% peak) in
// this very profile -> the machine has the BW; the sync structure wastes it.
// (Side lesson: VALUBusy was 30% vs 10% for identical work/time in R4/R7 --
// gfx950 derived counters fall back to gfx94x formulas; steer by dur/FETCH.)
// Round 9: remove ALL main-loop synchronization and LDS staging.
// Trick: split D_MODEL (not columns) across 4 lanes per row. Lane (row, phi)
// accumulates d in [4*phi, 4*phi+4) over all 784 cols:
//   - x: 4 phi-lanes issue the SAME address -> TA merges to one request; a
//     wave = 16 row-streams, each advancing 16B sequentially (unroll 4 = one
//     64B line back-to-back) -> every fetched line fully consumed, x read
//     exactly once GPU-wide, no LDS round trip.
//   - W: per-lane vector loads, 4 distinct addrs/wave shared by 16 lanes;
//     50KB -> L2-resident, ~800KB/CU total. No s_load uniformity needed.
//   - NO cross-lane reduction: each lane owns complete sums for its 4 d's.
//   - 784 = 196 float4 exactly -> no tail path.
// One __syncthreads in the whole kernel: gather acc[16]/row via LDS[64][17]
// (stride 17 -> 2 lanes/bank, free per m136), then the proven wave-0
// epilogue (bilinear blocks + head) unchanged from rounds 4-8.
// 1024 blocks x 256 thr (4 waves, 16 rows/wave), 16 waves/CU, VGPR cap 128.

#define IN_DIM   784
#define D_MODEL  16
#define HIDDEN   6
#define N_BLOCKS 4
#define N_CLS    10
#define BATCH    65536
#define NT       196       // float4 chunks per row (784/4, exact)

__global__ __launch_bounds__(256, 4) void bilinear_resnet_fused(
    const float* __restrict__ x,
    const float* __restrict__ W_embed,   // [16][784]
    const float* __restrict__ L_w,       // [4][6][16]
    const float* __restrict__ R_w,       // [4][6][16]
    const float* __restrict__ D_w,       // [4][16][6]
    const float* __restrict__ W_head,    // [10][16]
    float* __restrict__ out)
{
    __shared__ float accLDS[64][17];     // 4.3 KB, stride-17 conflict-free

    const int tid  = threadIdx.x;
    const int lane = tid & 63;
    const int wv   = tid >> 6;           // 0..3
    const int rloc = lane >> 2;          // 0..15: row within wave
    const int phi  = lane & 3;           // 0..3: d-slice [4phi, 4phi+4)
    const int rb   = wv * 16 + rloc;     // row within block 0..63
    const int row  = blockIdx.x * 64 + rb;

    const float* xr = x + (size_t)row * IN_DIM;
    const float* wr0 = W_embed + (size_t)(phi * 4 + 0) * IN_DIM;
    const float* wr1 = W_embed + (size_t)(phi * 4 + 1) * IN_DIM;
    const float* wr2 = W_embed + (size_t)(phi * 4 + 2) * IN_DIM;
    const float* wr3 = W_embed + (size_t)(phi * 4 + 3) * IN_DIM;

    float a0 = 0.f, a1 = 0.f, a2 = 0.f, a3 = 0.f;

    // main loop: barrier-free, LDS-free, fully pipelineable stream.
    // per t: 1 x-load (merged across 4 phi-lanes) + 4 W-loads (L2-hot)
    // + 16 FMAs. unroll 4 -> each row-stream consumes one 64B line
    // back-to-back; compiler hoists loads across groups for MLP.
#pragma unroll 4
    for (int t = 0; t < NT; ++t) {
        const float4 xv = *reinterpret_cast<const float4*>(xr  + 4 * t);
        const float4 w0 = *reinterpret_cast<const float4*>(wr0 + 4 * t);
        const float4 w1 = *reinterpret_cast<const float4*>(wr1 + 4 * t);
        const float4 w2 = *reinterpret_cast<const float4*>(wr2 + 4 * t);
        const float4 w3 = *reinterpret_cast<const float4*>(wr3 + 4 * t);
        a0 = fmaf(xv.w, w0.w, fmaf(xv.z, w0.z, fmaf(xv.y, w0.y, fmaf(xv.x, w0.x, a0))));
        a1 = fmaf(xv.w, w1.w, fmaf(xv.z, w1.z, fmaf(xv.y, w1.y, fmaf(xv.x, w1.x, a1))));
        a2 = fmaf(xv.w, w2.w, fmaf(xv.z, w2.z, fmaf(xv.y, w2.y, fmaf(xv.x, w2.x, a2))));
        a3 = fmaf(xv.w, w3.w, fmaf(xv.z, w3.z, fmaf(xv.y, w3.y, fmaf(xv.x, w3.x, a3))));
    }

    // gather the 4 d-slices per row
    accLDS[rb][phi * 4 + 0] = a0;
    accLDS[rb][phi * 4 + 1] = a1;
    accLDS[rb][phi * 4 + 2] = a2;
    accLDS[rb][phi * 4 + 3] = a3;
    __syncthreads();
    if (wv != 0) return;

    // ---- epilogue: wave 0, lane = row-in-block (64 lanes = 64 rows) ----
    float acc[D_MODEL];
#pragma unroll
    for (int d = 0; d < D_MODEL; ++d) acc[d] = accLDS[lane][d];

    const int erow = blockIdx.x * 64 + lane;

    // bilinear residual blocks (uniform weights -> scalar loads)
#pragma unroll
    for (int b = 0; b < N_BLOCKS; ++b) {
        const float* Lb = L_w + b * HIDDEN * D_MODEL;
        const float* Rb = R_w + b * HIDDEN * D_MODEL;
        const float* Db = D_w + b * D_MODEL * HIDDEN;
        float h[HIDDEN];
#pragma unroll
        for (int j = 0; j < HIDDEN; ++j) {
            float u = 0.f, v = 0.f;
#pragma unroll
            for (int d = 0; d < D_MODEL; ++d) {
                u = fmaf(acc[d], Lb[j * D_MODEL + d], u);
                v = fmaf(acc[d], Rb[j * D_MODEL + d], v);
            }
            h[j] = u * v;
        }
#pragma unroll
        for (int d = 0; d < D_MODEL; ++d) {
            float s = acc[d];
#pragma unroll
            for (int j = 0; j < HIDDEN; ++j) s = fmaf(h[j], Db[d * HIDDEN + j], s);
            acc[d] = s;
        }
        float* hout = out + (size_t)N_CLS * BATCH + (size_t)b * HIDDEN * BATCH
                      + (size_t)erow * HIDDEN;
#pragma unroll
        for (int j = 0; j < HIDDEN; ++j) hout[j] = h[j];
    }

    // head
    float* lout = out + (size_t)erow * N_CLS;
#pragma unroll
    for (int k = 0; k < N_CLS; ++k) {
        float s = 0.f;
#pragma unroll
        for (int d = 0; d < D_MODEL; ++d) s = fmaf(acc[d], W_head[k * D_MODEL + d], s);
        lout[k] = s;
    }
}

extern "C" void kernel_launch(void* const* d_in, const int* in_sizes, int n_in,
                              void* d_out, int out_size, void* d_ws, size_t ws_size,
                              hipStream_t stream) {
    const float* x       = (const float*)d_in[0];
    const float* W_embed = (const float*)d_in[1];
    const float* L_w     = (const float*)d_in[2];
    const float* R_w     = (const float*)d_in[3];
    const float* D_w     = (const float*)d_in[4];
    const float* W_head  = (const float*)d_in[5];
    float* out = (float*)d_out;

    const int grid = BATCH / 64;   // 1024 blocks x 256 threads (4 waves)
    bilinear_resnet_fused<<<grid, 256, 0, stream>>>(
        x, W_embed, L_w, R_w, D_w, W_head, out);
}